// Round 12
// baseline (185.513 us; speedup 1.0000x reference)
//
#include <hip/hip_runtime.h>

typedef unsigned int u32;
typedef unsigned long long u64;
typedef float f32x4 __attribute__((ext_vector_type(4)));

#define T_ 4
#define B_ 32
#define E_ 1024
#define H_ 16
#define HD_ 64
#define CACHE_ 4096
#define S_ 4100
#define SPLIT_ 4
#define NPART_ (SPLIT_ * 4)
#define NEGINF (-__builtin_inff())

// ---------------- prep: blocks 0..31 = mask compaction; 32..1567 = QKV proj ----------------
__global__ __launch_bounds__(256) void prep_kernel(
    const float* __restrict__ query,
    const float* __restrict__ Wq, const float* __restrict__ bq,
    const float* __restrict__ Wk, const float* __restrict__ bk,
    const float* __restrict__ Wv, const float* __restrict__ bv,
    const unsigned char* __restrict__ mask8,
    float* __restrict__ qs, float* __restrict__ kn, float* __restrict__ vn,
    int* __restrict__ cidx, int* __restrict__ ccnt, int* __restrict__ flag)
{
    const int tid = threadIdx.x;
    if (blockIdx.x < 32) {
        // ---------- compaction: 2 barriers total (pass0 counts, prefix, pass1 scatter) ----------
        const int b = blockIdx.x;
        const int w = tid >> 6, l = tid & 63;
        const int* mask32 = (const int*)mask8;
        __shared__ int cnt_s;
        __shared__ int rcnt[64];      // [round*4 + wave]
        __shared__ int roff[64];
        __shared__ int total_s;

        // mode detection over first 8KB of the mask buffer
        int cnt = 0;
        for (int i = tid; i < 8192; i += 256) cnt += (mask8[i] != 0) ? 1 : 0;
#pragma unroll
        for (int off = 32; off; off >>= 1) cnt += __shfl_xor(cnt, off);
        if (tid == 0) cnt_s = 0;
        __syncthreads();
        if (l == 0) atomicAdd(&cnt_s, cnt);
        __syncthreads();
        const int mode = (cnt_s > 2048) ? 1 : 0;
        if (b == 0 && tid == 0) *flag = mode;

        // pass 0: ballots + per-(round,wave) counts; ok bits cached in a register
        u32 okbits = 0;
        const size_t mbase = (size_t)b * S_;
#pragma unroll
        for (int r = 0; r < 16; r++) {
            int s = r * 256 + tid;
            bool ok = mode ? (mask8[mbase + s] == 0) : (mask32[mbase + s] == 0);
            okbits |= (ok ? 1u : 0u) << r;
            u64 bal = __ballot(ok);
            if (l == 0) rcnt[r * 4 + w] = (int)__popcll(bal);
        }
        __syncthreads();
        // exclusive prefix over the 64 counts (wave 0)
        if (tid < 64) {
            int c = rcnt[tid];
            int incl = c;
#pragma unroll
            for (int d = 1; d < 64; d <<= 1) {
                int v = __shfl_up(incl, d);
                if (l >= d) incl += v;
            }
            roff[tid] = incl - c;
            if (tid == 63) total_s = incl;
        }
        __syncthreads();
        // pass 1: barrier-free scatter
#pragma unroll
        for (int r = 0; r < 16; r++) {
            bool ok = (okbits >> r) & 1;
            u64 bal = __ballot(ok);
            int pre = (int)__popcll(bal & ((1ull << l) - 1));
            if (ok) cidx[b * CACHE_ + roff[r * 4 + w] + pre] = r * 256 + tid;
        }
        if (tid == 0) ccnt[b] = total_s;
        return;
    }

    // ---------- QKV projection, 16x16 tiles, BK=64 ----------
    const int bx = blockIdx.x - 32;       // 0..1535
    const int mat = bx >> 9;              // 0..2 (512 blocks each)
    const int rem = bx & 511;
    const int rt = rem >> 6, ct = rem & 63;
    const int r0 = rt * 16, c0 = ct * 16;
    const float* W    = (mat == 0) ? Wq : (mat == 1) ? Wk : Wv;
    const float* bias = (mat == 0) ? bq : (mat == 1) ? bk : bv;

    __shared__ float A_l[16][65];
    __shared__ float W_l[16][65];
    const int r = tid >> 4, cc = tid & 15;
    float acc = 0.f;

    for (int k0 = 0; k0 < 1024; k0 += 64) {
        __syncthreads();
        if (tid < 128) {
            int j0 = tid * 2;
#pragma unroll
            for (int jj = 0; jj < 2; jj++) {
                int j = j0 + jj;
                int ar = j >> 4, kk = (j & 15) * 4;
                float4 v = *(const float4*)(query + (size_t)(r0 + ar) * 1024 + k0 + kk);
                A_l[ar][kk] = v.x; A_l[ar][kk + 1] = v.y;
                A_l[ar][kk + 2] = v.z; A_l[ar][kk + 3] = v.w;
            }
        } else {
            int j0 = (tid - 128) * 2;
#pragma unroll
            for (int jj = 0; jj < 2; jj++) {
                int j = j0 + jj;
                int wr = j >> 4, kk = (j & 15) * 4;
                float4 v = *(const float4*)(W + (size_t)(c0 + wr) * 1024 + k0 + kk);
                W_l[wr][kk] = v.x; W_l[wr][kk + 1] = v.y;
                W_l[wr][kk + 2] = v.z; W_l[wr][kk + 3] = v.w;
            }
        }
        __syncthreads();
#pragma unroll
        for (int kk = 0; kk < 64; kk++) acc += A_l[r][kk] * W_l[cc][kk];
    }
    const int row = r0 + r, col = c0 + cc;
    const int t = row >> 5, b = row & 31;
    const int h = col >> 6, d = col & 63;
    float val = acc + bias[col];
    size_t oidx = ((size_t)((b * H_ + h) * T_ + t)) * HD_ + d;
    if (mat == 0) qs[oidx] = val * 0.125f;
    else if (mat == 1) kn[oidx] = val;
    else vn[oidx] = val;
}

// ---------------- attention: 256B-transaction, lane-local-softmax flash decode ----------------
// Lane (r4 = l>>4, s16 = l&15): dims {s16*4..+3}; per chunk of 32 rows the wave
// owns rows w*8 + {r4, r4+4}. Each K/V load instr = 4 groups x 16 lanes x 16B
// = 4 contiguous 256B row-transactions (half the request count of the 128B map).
// Lane-local online softmax (per its 2 row-slots); end-merge over lane bits 4,5.
__global__ __launch_bounds__(256, 4) void attn_kernel(
    const float* __restrict__ kcache, const float* __restrict__ vcache,
    const float* __restrict__ qs,
    const int* __restrict__ cidx, const int* __restrict__ ccnt,
    float* __restrict__ part_ml, float* __restrict__ part_acc)
{
    const int bid = blockIdx.x;
    const int bh = bid >> 2, split = bid & 3;
    const int b = bh >> 4;
    const int tid = threadIdx.x;
    const int w = tid >> 6, l = tid & 63;
    const int s16 = l & 15, r4 = l >> 4;

    __shared__ float q_l[256];
    __shared__ int cidx_l[1056];

    const int cnt = ccnt[b];
    const int qsz = (cnt + 3) >> 2;
    const int lo = split * qsz;
    const int hi = min(cnt, lo + qsz);
    const int n = (hi > lo) ? (hi - lo) : 0;

    q_l[tid] = qs[bh * 256 + tid];
    for (int i = tid; i < n; i += 256) cidx_l[i] = cidx[b * CACHE_ + lo + i];
    __syncthreads();

    float4 qf[4];
#pragma unroll
    for (int t = 0; t < 4; t++) qf[t] = *(const float4*)&q_l[t * 64 + s16 * 4];

    f32x4 o[4];
#pragma unroll
    for (int t = 0; t < 4; t++) { o[t].x = 0.f; o[t].y = 0.f; o[t].z = 0.f; o[t].w = 0.f; }
    float m[4] = {NEGINF, NEGINF, NEGINF, NEGINF};
    float L[4] = {0.f, 0.f, 0.f, 0.f};

    const float* kb = kcache + (size_t)bh * (CACHE_ * HD_) + s16 * 4;
    const float* vb = vcache + (size_t)bh * (CACHE_ * HD_) + s16 * 4;

    const int nch = (n + 31) >> 5;
    const int pA = w * 8 + r4;
    const int pB = w * 8 + 4 + r4;

    f32x4 kA0, kA1, vA0, vA1, kB0, kB1, vB0, vB1;

#define ISSUE(K0, K1, V0, V1, CC) {                                             \
        int iA_ = cidx_l[min((CC) * 32 + pA, n - 1)];                           \
        int iB_ = cidx_l[min((CC) * 32 + pB, n - 1)];                           \
        K0 = __builtin_nontemporal_load((const f32x4*)(kb + ((size_t)iA_ << 6))); \
        K1 = __builtin_nontemporal_load((const f32x4*)(kb + ((size_t)iB_ << 6))); \
        V0 = __builtin_nontemporal_load((const f32x4*)(vb + ((size_t)iA_ << 6))); \
        V1 = __builtin_nontemporal_load((const f32x4*)(vb + ((size_t)iB_ << 6))); \
    }

#define PROCESS(K0, K1, V0, V1, CC) {                                               \
        const bool vA_ = ((CC) * 32 + pA) < n;                                      \
        const bool vB_ = ((CC) * 32 + pB) < n;                                      \
        _Pragma("unroll")                                                           \
        for (int t = 0; t < 4; t++) {                                               \
            float pa_ = qf[t].x * K0.x + qf[t].y * K0.y                             \
                      + qf[t].z * K0.z + qf[t].w * K0.w;                            \
            float pb_ = qf[t].x * K1.x + qf[t].y * K1.y                             \
                      + qf[t].z * K1.z + qf[t].w * K1.w;                            \
            pa_ += __shfl_xor(pa_, 1); pa_ += __shfl_xor(pa_, 2);                   \
            pa_ += __shfl_xor(pa_, 4); pa_ += __shfl_xor(pa_, 8);                   \
            pb_ += __shfl_xor(pb_, 1); pb_ += __shfl_xor(pb_, 2);                   \
            pb_ += __shfl_xor(pb_, 4); pb_ += __shfl_xor(pb_, 8);                   \
            float sA_ = vA_ ? pa_ : NEGINF;                                         \
            float sB_ = vB_ ? pb_ : NEGINF;                                         \
            float mx_ = fmaxf(sA_, sB_);                                            \
            if (mx_ > m[t] + 8.f) {     /* defer-max: rare rescale */               \
                float fac_ = __expf(m[t] - mx_);                                    \
                L[t] *= fac_;                                                       \
                o[t].x *= fac_; o[t].y *= fac_; o[t].z *= fac_; o[t].w *= fac_;     \
                m[t] = mx_;                                                         \
            }                                                                       \
            float eA_ = (sA_ == NEGINF) ? 0.f : __expf(sA_ - m[t]);                 \
            float eB_ = (sB_ == NEGINF) ? 0.f : __expf(sB_ - m[t]);                 \
            L[t] += eA_ + eB_;                                                      \
            o[t].x += eA_ * V0.x + eB_ * V1.x;                                      \
            o[t].y += eA_ * V0.y + eB_ * V1.y;                                      \
            o[t].z += eA_ * V0.z + eB_ * V1.z;                                      \
            o[t].w += eA_ * V0.w + eB_ * V1.w;                                      \
        }                                                                           \
    }

    if (nch > 0) ISSUE(kA0, kA1, vA0, vA1, 0);
    if (nch > 1) ISSUE(kB0, kB1, vB0, vB1, 1);

    for (int c = 0; c < nch; c += 2) {
        PROCESS(kA0, kA1, vA0, vA1, c);
        if (c + 2 < nch) ISSUE(kA0, kA1, vA0, vA1, c + 2);
        if (c + 1 < nch) {
            PROCESS(kB0, kB1, vB0, vB1, c + 1);
            if (c + 3 < nch) ISSUE(kB0, kB1, vB0, vB1, c + 3);
        }
    }
#undef ISSUE
#undef PROCESS

    // ---- end merge across row-groups: lanes differ in bits 4,5 (r4) ----
    const int pidx = bid * 4 + w;           // [0, 8192)
#pragma unroll
    for (int t = 0; t < 4; t++) {
        float M = m[t];
        M = fmaxf(M, __shfl_xor(M, 16));
        M = fmaxf(M, __shfl_xor(M, 32));
        float fac = (m[t] == NEGINF) ? 0.f : __expf(m[t] - M);
        float Lr = L[t] * fac;
        Lr += __shfl_xor(Lr, 16);
        Lr += __shfl_xor(Lr, 32);
        float ax = o[t].x * fac, ay = o[t].y * fac,
              az = o[t].z * fac, aw = o[t].w * fac;
#pragma unroll
        for (int off = 16; off <= 32; off <<= 1) {
            ax += __shfl_xor(ax, off); ay += __shfl_xor(ay, off);
            az += __shfl_xor(az, off); aw += __shfl_xor(aw, off);
        }
        if (r4 == 0) {
            *(float4*)&part_acc[((size_t)pidx * 4 + t) * HD_ + s16 * 4] =
                make_float4(ax, ay, az, aw);
        }
        if (l == 0) {
            part_ml[pidx * 8 + t * 2 + 0] = M;
            part_ml[pidx * 8 + t * 2 + 1] = Lr;
        }
    }
}

// ---------------- merge partials + new tokens + normalize ----------------
__global__ __launch_bounds__(256) void merge_kernel(
    const float* __restrict__ part_ml, const float* __restrict__ part_acc,
    const float* __restrict__ qs, const float* __restrict__ kn,
    const float* __restrict__ vn,
    const unsigned char* __restrict__ mask8, const int* __restrict__ flag,
    float* __restrict__ attn_out)
{
    const int bh = blockIdx.x;
    const int b = bh >> 4, h = bh & 15;
    const int tid = threadIdx.x;
    const int t = tid >> 6, d = tid & 63;
    const int mode = *flag;
    const int* mask32 = (const int*)mask8;

    float M = NEGINF;
#pragma unroll
    for (int i = 0; i < NPART_; i++)
        M = fmaxf(M, part_ml[(bh * NPART_ + i) * 8 + t * 2]);
    float acc = 0.f, L = 0.f;
#pragma unroll
    for (int i = 0; i < NPART_; i++) {
        float mi = part_ml[(bh * NPART_ + i) * 8 + t * 2];
        float li = part_ml[(bh * NPART_ + i) * 8 + t * 2 + 1];
        if (mi > NEGINF) {
            float wgt = __expf(mi - M);
            L += li * wgt;
            acc += part_acc[((size_t)(bh * NPART_ + i) * 4 + t) * HD_ + d] * wgt;
        }
    }

    // new-token keys (positions CACHE_..CACHE_+3)
    float qv = qs[bh * 256 + t * 64 + d];
    float sn[4];
#pragma unroll
    for (int i = 0; i < 4; i++) {
        size_t mi_ = (size_t)b * S_ + CACHE_ + i;
        bool masked = mode ? (mask8[mi_] != 0) : (mask32[mi_] != 0);
        float prod = qv * kn[bh * 256 + i * 64 + d];
        prod += __shfl_xor(prod, 1);
        prod += __shfl_xor(prod, 2);
        prod += __shfl_xor(prod, 4);
        prod += __shfl_xor(prod, 8);
        prod += __shfl_xor(prod, 16);
        prod += __shfl_xor(prod, 32);
        sn[i] = masked ? NEGINF : prod;
    }
    float M2 = M;
#pragma unroll
    for (int i = 0; i < 4; i++) M2 = fmaxf(M2, sn[i]);
    if (M2 > NEGINF) {
        if (M > NEGINF) {
            float wo = __expf(M - M2);
            acc *= wo; L *= wo;
        }
#pragma unroll
        for (int i = 0; i < 4; i++) {
            if (sn[i] > NEGINF) {
                float e = __expf(sn[i] - M2);
                L += e;
                acc += e * vn[bh * 256 + i * 64 + d];
            }
        }
    }
    float o = (L > 0.f) ? acc / L : 0.f;
    attn_out[(size_t)(t * B_ + b) * E_ + h * HD_ + d] = o;
}

// ---------------- output projection, 16x16 tiles, BK=64 (512 blocks) ----------------
__global__ __launch_bounds__(256) void oproj_kernel(
    const float* __restrict__ A,
    const float* __restrict__ W, const float* __restrict__ bias,
    float* __restrict__ out)
{
    const int bx = blockIdx.x;            // 512 blocks: 8 rt x 64 ct
    const int rt = bx >> 6, ct = bx & 63;
    const int r0 = rt * 16, c0 = ct * 16;
    const int tid = threadIdx.x;

    __shared__ float A_l[16][65];
    __shared__ float W_l[16][65];
    const int r = tid >> 4, cc = tid & 15;
    float acc = 0.f;

    for (int k0 = 0; k0 < 1024; k0 += 64) {
        __syncthreads();
        if (tid < 128) {
            int j0 = tid * 2;
#pragma unroll
            for (int jj = 0; jj < 2; jj++) {
                int j = j0 + jj;
                int ar = j >> 4, kk = (j & 15) * 4;
                float4 v = *(const float4*)(A + (size_t)(r0 + ar) * 1024 + k0 + kk);
                A_l[ar][kk] = v.x; A_l[ar][kk + 1] = v.y;
                A_l[ar][kk + 2] = v.z; A_l[ar][kk + 3] = v.w;
            }
        } else {
            int j0 = (tid - 128) * 2;
#pragma unroll
            for (int jj = 0; jj < 2; jj++) {
                int j = j0 + jj;
                int wr = j >> 4, kk = (j & 15) * 4;
                float4 v = *(const float4*)(W + (size_t)(c0 + wr) * 1024 + k0 + kk);
                W_l[wr][kk] = v.x; W_l[wr][kk + 1] = v.y;
                W_l[wr][kk + 2] = v.z; W_l[wr][kk + 3] = v.w;
            }
        }
        __syncthreads();
#pragma unroll
        for (int kk = 0; kk < 64; kk++) acc += A_l[r][kk] * W_l[cc][kk];
    }
    const int row = r0 + r, col = c0 + cc;
    out[(size_t)row * 1024 + col] = acc + bias[col];
}

extern "C" void kernel_launch(void* const* d_in, const int* in_sizes, int n_in,
                              void* d_out, int out_size, void* d_ws, size_t ws_size,
                              hipStream_t stream) {
    const float* query = (const float*)d_in[0];
    // d_in[1] = key: unused by the reference (k_new/v_new project from query)
    const unsigned char* mask = (const unsigned char*)d_in[2];
    const float* kcache = (const float*)d_in[3];
    const float* vcache = (const float*)d_in[4];
    const float* Wq = (const float*)d_in[5];
    const float* bq = (const float*)d_in[6];
    const float* Wk = (const float*)d_in[7];
    const float* bk = (const float*)d_in[8];
    const float* Wv = (const float*)d_in[9];
    const float* bv = (const float*)d_in[10];
    const float* Wo = (const float*)d_in[11];
    const float* bo = (const float*)d_in[12];

    char* ws = (char*)d_ws;
    float* qs   = (float*)(ws);                       // 512 KB
    float* kn   = (float*)(ws + ( 512ull << 10));     // 512 KB
    float* vn   = (float*)(ws + (1024ull << 10));     // 512 KB
    float* att  = (float*)(ws + (1536ull << 10));     // 512 KB
    int*   flag = (int*)  (ws + (2048ull << 10));     // 4 B
    int*   cidx = (int*)  (ws + (2049ull << 10));     // 512 KB
    int*   ccnt = (int*)  (ws + (2562ull << 10));     // 128 B
    float* pml  = (float*)(ws + (2563ull << 10));     // 256 KB
    float* pacc = (float*)(ws + (3072ull << 10));     // 8 MB

    prep_kernel<<<32 + 1536, 256, 0, stream>>>(query, Wq, bq, Wk, bk, Wv, bv,
                                               mask, qs, kn, vn, cidx, ccnt, flag);
    attn_kernel<<<512 * SPLIT_, 256, 0, stream>>>(kcache, vcache, qs, cidx, ccnt, pml, pacc);
    merge_kernel<<<512, 256, 0, stream>>>(pml, pacc, qs, kn, vn, mask, flag, att);
    oproj_kernel<<<512, 256, 0, stream>>>(att, Wo, bo, (float*)d_out);
}